// Round 9
// baseline (68.915 us; speedup 1.0000x reference)
//
#include <hip/hip_runtime.h>

// Problem constants (fixed by reference setup_inputs)
#define NB 32
#define NC 128
#define NH 63
#define NW 63
#define HW (NH*NW)       // 3969
#define OH 30            // (63-5)/2+1
#define OW 30
#define SEGW 19          // band cols per segment (tiles 8g..8g+7 -> cols 16g..16g+18)
#define POSN (5*SEGW)    // 95 band positions
#define NTHR 128
#define NSEG 4
#define NBLK (NB*OH*NSEG)   // 3840

// Band row = 16 floats (64B); granule swizzle rotates the four float4 slots with
// position: slot = (c4 + (pos>>1)) & 3.
__device__ __forceinline__ int bnd(int pos, int c4) {
    return pos * 16 + (((c4 + (pos >> 1)) & 3) << 2);
}

__global__ void init_tops(float* tops) {
    if (threadIdx.x < NB) tops[threadIdx.x] = 0.0f;
}

// s[tile][p] = 1 - (1/25) * e_p . S_tile,  e = f/||f||,  S = sum of window's 25 e.
// NOTE: bare launch_bounds — a min-waves clause collapses the VGPR budget below
// the live set and spills (R6: 2.6 GB scratch, R7: 58 MB scratch).
__global__ __launch_bounds__(NTHR) void seg_kernel(const float* __restrict__ f,
                                                   float* __restrict__ tops) {
    // XCD-chunked swizzle (bijective: 3840 = 8*480). Consecutive logical blocks =
    // the 4 segments of one strip, then adjacent strips -> same-XCD L2 reuse.
    const int lb    = (blockIdx.x & 7) * (NBLK / 8) + (blockIdx.x >> 3);
    const int strip = lb >> 2;
    const int g     = lb & 3;            // tiles 8g..8g+7 (g=3: 24..29 valid)
    const int b     = strip / OH;
    const int oi    = strip % OH;
    const int y0    = oi * 2;
    const int xlo   = 16 * g;
    const int t     = threadIdx.x;

    __shared__ __align__(16) float band[POSN * 16];   // 6.08 KB normalized chunk
    __shared__ __align__(16) float Sl[8 * 16];        // per-tile window sums
    __shared__ float wmax[2];

    // ---- staging geometry: thread t<95 owns band position t = (sr, sxx) ----
    const int  sr   = (t < POSN) ? t / SEGW : 0;
    const int  sxx  = (t < POSN) ? t % SEGW : 0;
    const bool sval = (t < POSN) && (xlo + sxx < NW);
    const float* gp = f + (size_t)b * NC * HW + (size_t)(y0 + sr) * NW + xlo + sxx;

    // ---- pass 1: sumsq over 128 channels; finish on ch 0..15, keep them in regs ----
    float sumsq = 0.0f;
    float v[16];
    if (sval) {
        const float* p = gp + (size_t)16 * HW;
        #pragma unroll 16
        for (int c = 16; c < NC; ++c) { const float x = *p; p += HW; sumsq = fmaf(x, x, sumsq); }
        #pragma unroll
        for (int k = 0; k < 16; ++k) v[k] = gp[(size_t)k * HW];
        #pragma unroll
        for (int k = 0; k < 16; ++k) sumsq = fmaf(v[k], v[k], sumsq);
    }
    const float inv = (sval && sumsq > 0.0f) ? rsqrtf(sumsq) : 0.0f;

    // ---- dot geometry: thread t<100 owns items 2t, 2t+1 of 8*25=200 ----
    const bool dthr  = t < 100;
    const int  it0   = 2 * t, it1 = 2 * t + 1;
    const int  tl0   = it0 / 25, p0 = it0 % 25;
    const int  tl1   = it1 / 25, p1 = it1 % 25;
    const bool val0  = dthr && (8 * g + tl0 < OH);
    const bool val1  = dthr && (8 * g + tl1 < OH);
    const int  pos0  = (p0 / 5) * SEGW + 2 * tl0 + (p0 % 5);
    const int  pos1  = (p1 / 5) * SEGW + 2 * tl1 + (p1 % 5);
    float acc0 = 0.0f, acc1 = 0.0f;

    // ---- pass 2: 8 channel-chunks; prefetch chunk ch+1 under S-sum + dots ----
    #pragma unroll 1
    for (int ch = 0; ch < 8; ++ch) {
        __syncthreads();                       // prev chunk's readers done
        if (sval) {
            #pragma unroll
            for (int c4 = 0; c4 < 4; ++c4) {
                const float4 e = {v[4*c4] * inv, v[4*c4+1] * inv,
                                  v[4*c4+2] * inv, v[4*c4+3] * inv};
                *(float4*)&band[bnd(t, c4)] = e;
            }
        }
        __syncthreads();                       // band ready
        if (ch < 7 && sval) {                  // issue next chunk's globals early
            const float* p = gp + (size_t)((ch + 1) * 16) * HW;
            #pragma unroll
            for (int k = 0; k < 16; ++k) v[k] = p[(size_t)k * HW];
        }
        if (t < 32) {                          // per-tile window sums S
            const int tl = t >> 2, c4 = t & 3;
            float4 s = {0.0f, 0.0f, 0.0f, 0.0f};
            #pragma unroll
            for (int r = 0; r < 5; ++r)
                #pragma unroll
                for (int k = 0; k < 5; ++k) {
                    const float4 e = *(const float4*)&band[bnd(r * SEGW + 2 * tl + k, c4)];
                    s.x += e.x; s.y += e.y; s.z += e.z; s.w += e.w;
                }
            *(float4*)&Sl[tl * 16 + c4 * 4] = s;
        }
        __syncthreads();                       // S ready
        if (dthr) {
            float4 sv[4];
            #pragma unroll
            for (int c4 = 0; c4 < 4; ++c4) sv[c4] = *(const float4*)&Sl[tl0 * 16 + c4 * 4];
            #pragma unroll
            for (int c4 = 0; c4 < 4; ++c4) {
                const float4 e = *(const float4*)&band[bnd(pos0, c4)];
                acc0 += e.x * sv[c4].x + e.y * sv[c4].y + e.z * sv[c4].z + e.w * sv[c4].w;
            }
            if (tl1 != tl0) {
                #pragma unroll
                for (int c4 = 0; c4 < 4; ++c4) sv[c4] = *(const float4*)&Sl[tl1 * 16 + c4 * 4];
            }
            #pragma unroll
            for (int c4 = 0; c4 < 4; ++c4) {
                const float4 e = *(const float4*)&band[bnd(pos1, c4)];
                acc1 += e.x * sv[c4].x + e.y * sv[c4].y + e.z * sv[c4].z + e.w * sv[c4].w;
            }
        }
    }

    // ---- epilogue: masked max over valid items (s >= 0 always), one atomic ----
    float m = 0.0f;
    if (val0) m = fmaxf(m, 1.0f - acc0 * 0.04f);
    if (val1) m = fmaxf(m, 1.0f - acc1 * 0.04f);
    #pragma unroll
    for (int off = 1; off < 64; off <<= 1) m = fmaxf(m, __shfl_xor(m, off));
    if ((t & 63) == 0) wmax[t >> 6] = m;
    __syncthreads();
    if (t == 0) {
        m = fmaxf(m, wmax[1]);
        atomicMax((int*)&tops[b], __float_as_int(m));   // m >= 0, int-pun valid
    }
}

__global__ void finalize(const float* __restrict__ tops,
                         const int* __restrict__ label,
                         float* __restrict__ out) {
    if (threadIdx.x == 0) {
        float fs = 0.0f, rs = 0.0f, fc = 0.0f, rc = 0.0f;
        for (int b = 0; b < NB; ++b) {
            const float tb  = tops[b];
            const float lbv = (float)label[b];
            fs += tb * lbv;          fc += lbv;
            rs += tb * (1.0f - lbv); rc += (1.0f - lbv);
        }
        const float loss = 1.0f - fs / fc + rs / rc;
        out[0] = fmaxf(loss, 0.0f);
    }
}

extern "C" void kernel_launch(void* const* d_in, const int* in_sizes, int n_in,
                              void* d_out, int out_size, void* d_ws, size_t ws_size,
                              hipStream_t stream) {
    const float* feature = (const float*)d_in[0];
    const int* label     = (const int*)d_in[1];
    float* out  = (float*)d_out;
    float* tops = (float*)d_ws;   // 32 floats of scratch

    init_tops<<<1, 64, 0, stream>>>(tops);
    seg_kernel<<<NBLK, NTHR, 0, stream>>>(feature, tops);
    finalize<<<1, 64, 0, stream>>>(tops, label, out);
}

// Round 10
// 68.599 us; speedup vs baseline: 1.0046x; 1.0046x over previous
//
#include <hip/hip_runtime.h>
#include <hip/hip_bf16.h>

// Problem constants (fixed by reference setup_inputs)
#define NB 32
#define NC 128
#define NH 63
#define NW 63
#define HW 3969          // 63*63
#define NPIX 3969
#define OH 30            // (63-5)/2+1
#define OW 30
#define SEGW 19          // band cols per segment (tiles 8g..8g+7 -> cols 16g..16g+18)
#define POSN (5*SEGW)    // 95
#define NSEG 4
#define NSTRIP (NB*OH)   // 960
#define NBLK (NSTRIP*NSEG) // 3840

// ws layout (bytes):
//   [0, 15360)        : 3840 per-block result slots (float)  -- all written each launch
//   [15360, 523392)   : inv-norm map, 32*3969 floats
//   [523392, +32.5MB) : bf16 e-copy, 32*3969*64 uints (big path only)
#define MAP_OFF  ((size_t)NBLK * 4)
#define E_OFF    (MAP_OFF + (size_t)NB * NPIX * 4)
#define E_BYTES  ((size_t)NB * NPIX * 64 * 4)
#define WS_BIG_NEED (E_OFF + E_BYTES)

// ---------------- k1: per-pixel inv-norm (+ optional bf16 e-copy) ----------------
// 8 threads per pixel (16 channels each); block = 32 pixels.
template<int BIG>
__global__ __launch_bounds__(256) void norm_kernel(const float* __restrict__ f,
                                                   float* __restrict__ map,
                                                   unsigned* __restrict__ e) {
    const int b      = blockIdx.x / 125;
    const int grp    = blockIdx.x % 125;
    const int t      = threadIdx.x;
    const int chunk  = t >> 5;           // 0..7 -> channels 16*chunk..+15
    const int pixloc = t & 31;
    const int pix    = grp * 32 + pixloc;
    const bool valid = pix < NPIX;

    __shared__ float sq[32];
    if (t < 32) sq[t] = 0.0f;
    __syncthreads();

    float v[16]; float ss = 0.0f;
    if (valid) {
        const float* p = f + (size_t)b * NC * HW + (size_t)chunk * 16 * HW + pix;
        #pragma unroll
        for (int k = 0; k < 16; ++k) v[k] = p[(size_t)k * HW];
        #pragma unroll
        for (int k = 0; k < 16; ++k) ss = fmaf(v[k], v[k], ss);
        atomicAdd(&sq[pixloc], ss);
    }
    __syncthreads();
    if (valid) {
        const float inv = rsqrtf(fmaxf(sq[pixloc], 1e-24f));
        if (chunk == 0) map[b * NPIX + pix] = inv;
        if (BIG) {
            unsigned u[8];
            #pragma unroll
            for (int j = 0; j < 8; ++j) {
                __hip_bfloat162 h2 = __float22bfloat162_rn(
                    make_float2(v[2*j] * inv, v[2*j+1] * inv));
                u[j] = *reinterpret_cast<unsigned*>(&h2);
            }
            unsigned* dst = e + ((size_t)b * NPIX + pix) * 64 + chunk * 8;
            *(uint4*)dst       = make_uint4(u[0], u[1], u[2], u[3]);
            *(uint4*)(dst + 4) = make_uint4(u[4], u[5], u[6], u[7]);
        }
    }
}

// bf16x2 unpack (exact): low 16 bits = first channel
__device__ __forceinline__ float blo(unsigned u) { return __uint_as_float(u << 16); }
__device__ __forceinline__ float bhi(unsigned u) { return __uint_as_float(u & 0xffff0000u); }

// ---------------- k2 (big): single-stage bf16 segment kernel ----------------
// s[tile][p] = 1 - (1/25) e_p . S_tile. Band swizzle: granule (slot+pos)&15,
// identical on write and read.
__global__ __launch_bounds__(128) void seg_bf16_kernel(const unsigned* __restrict__ e,
                                                       float* __restrict__ slots) {
    const int lb    = (blockIdx.x & 7) * (NBLK / 8) + (blockIdx.x >> 3);
    const int strip = lb >> 2, g = lb & 3;
    const int b = strip / OH, oi = strip % OH;
    const int y0 = oi * 2, xlo = 16 * g;
    const int t = threadIdx.x;

    __shared__ unsigned band[POSN * 64];   // 24320 B: [pos][64 uints = 128 bf16]
    __shared__ float Sl[16 * 64];          // 4 KB: [slot][tl][8 floats]
    __shared__ float wmax[2];

    const unsigned* eb = e + (size_t)b * NPIX * 64;

    // ---- stage whole band (12 coalesced rounds) ----
    #pragma unroll 1
    for (int i = t; i < POSN * 16; i += 128) {
        const int pos = i >> 4, slot = i & 15;
        const int r = pos / SEGW, xx = pos - r * SEGW;
        const int x = xlo + xx;
        uint4 v = make_uint4(0u, 0u, 0u, 0u);
        if (x < NW) v = *(const uint4*)(eb + (size_t)((y0 + r) * NW + x) * 64 + slot * 4);
        *(uint4*)&band[pos * 64 + (((slot + pos) & 15) << 2)] = v;
    }
    __syncthreads();

    // ---- S sums: thread (tl = t>>4, slot = t&15) owns 8 channels of one tile ----
    {
        const int tl = t >> 4, slot = t & 15;
        float s[8];
        #pragma unroll
        for (int j = 0; j < 8; ++j) s[j] = 0.0f;
        #pragma unroll
        for (int r = 0; r < 5; ++r)
            #pragma unroll
            for (int k = 0; k < 5; ++k) {
                const int pos = r * SEGW + 2 * tl + k;
                const uint4 v = *(const uint4*)&band[pos * 64 + (((slot + pos) & 15) << 2)];
                s[0] += blo(v.x); s[1] += bhi(v.x);
                s[2] += blo(v.y); s[3] += bhi(v.y);
                s[4] += blo(v.z); s[5] += bhi(v.z);
                s[6] += blo(v.w); s[7] += bhi(v.w);
            }
        float* d = &Sl[slot * 64 + tl * 8];
        *(float4*)d       = make_float4(s[0], s[1], s[2], s[3]);
        *(float4*)(d + 4) = make_float4(s[4], s[5], s[6], s[7]);
    }
    __syncthreads();

    // ---- dots: thread t<100 owns items 2t, 2t+1 of 8*25 ----
    float m = 0.0f;
    if (t < 100) {
        const int it0 = 2 * t, it1 = 2 * t + 1;
        const int tl0 = it0 / 25, p0 = it0 % 25;
        const int tl1 = it1 / 25, p1 = it1 % 25;
        const bool val0 = (8 * g + tl0 < OH);
        const bool val1 = (8 * g + tl1 < OH);
        const int pos0 = (p0 / 5) * SEGW + 2 * tl0 + (p0 % 5);
        const int pos1 = (p1 / 5) * SEGW + 2 * tl1 + (p1 % 5);
        float acc0 = 0.0f, acc1 = 0.0f;
        #pragma unroll
        for (int slot = 0; slot < 16; ++slot) {
            const float4 sA = *(const float4*)&Sl[slot * 64 + tl0 * 8];
            const float4 sB = *(const float4*)&Sl[slot * 64 + tl0 * 8 + 4];
            const uint4 v = *(const uint4*)&band[pos0 * 64 + (((slot + pos0) & 15) << 2)];
            acc0 = fmaf(blo(v.x), sA.x, acc0); acc0 = fmaf(bhi(v.x), sA.y, acc0);
            acc0 = fmaf(blo(v.y), sA.z, acc0); acc0 = fmaf(bhi(v.y), sA.w, acc0);
            acc0 = fmaf(blo(v.z), sB.x, acc0); acc0 = fmaf(bhi(v.z), sB.y, acc0);
            acc0 = fmaf(blo(v.w), sB.z, acc0); acc0 = fmaf(bhi(v.w), sB.w, acc0);
        }
        #pragma unroll
        for (int slot = 0; slot < 16; ++slot) {
            const float4 sA = *(const float4*)&Sl[slot * 64 + tl1 * 8];
            const float4 sB = *(const float4*)&Sl[slot * 64 + tl1 * 8 + 4];
            const uint4 v = *(const uint4*)&band[pos1 * 64 + (((slot + pos1) & 15) << 2)];
            acc1 = fmaf(blo(v.x), sA.x, acc1); acc1 = fmaf(bhi(v.x), sA.y, acc1);
            acc1 = fmaf(blo(v.y), sA.z, acc1); acc1 = fmaf(bhi(v.y), sA.w, acc1);
            acc1 = fmaf(blo(v.z), sB.x, acc1); acc1 = fmaf(bhi(v.z), sB.y, acc1);
            acc1 = fmaf(blo(v.w), sB.z, acc1); acc1 = fmaf(bhi(v.w), sB.w, acc1);
        }
        if (val0) m = fmaxf(m, 1.0f - acc0 * 0.04f);
        if (val1) m = fmaxf(m, 1.0f - acc1 * 0.04f);
    }
    #pragma unroll
    for (int off = 1; off < 64; off <<= 1) m = fmaxf(m, __shfl_xor(m, off));
    if ((t & 63) == 0) wmax[t >> 6] = m;
    __syncthreads();
    if (t == 0) slots[lb] = fmaxf(wmax[0], wmax[1]);   // >= 0 by construction
}

// ---------------- k2 (fallback): R9 chunked fp32 kernel, pass-1 via map ----------------
__device__ __forceinline__ int bnd(int pos, int c4) {
    return pos * 16 + (((c4 + (pos >> 1)) & 3) << 2);
}

__global__ __launch_bounds__(128) void seg_f32_kernel(const float* __restrict__ f,
                                                      const float* __restrict__ map,
                                                      float* __restrict__ slots) {
    const int lb    = (blockIdx.x & 7) * (NBLK / 8) + (blockIdx.x >> 3);
    const int strip = lb >> 2, g = lb & 3;
    const int b = strip / OH, oi = strip % OH;
    const int y0 = oi * 2, xlo = 16 * g;
    const int t = threadIdx.x;

    __shared__ __align__(16) float band[POSN * 16];
    __shared__ __align__(16) float Sl[8 * 16];
    __shared__ float wmax[2];

    const int  sr   = (t < POSN) ? t / SEGW : 0;
    const int  sxx  = (t < POSN) ? t % SEGW : 0;
    const bool sval = (t < POSN) && (xlo + sxx < NW);
    const float* gp = f + (size_t)b * NC * HW + (size_t)(y0 + sr) * NW + xlo + sxx;
    const float inv = sval ? map[b * NPIX + (y0 + sr) * NW + xlo + sxx] : 0.0f;

    float v[16];
    if (sval) {
        #pragma unroll
        for (int k = 0; k < 16; ++k) v[k] = gp[(size_t)k * HW];
    }

    const bool dthr = t < 100;
    const int it0 = 2 * t, it1 = 2 * t + 1;
    const int tl0 = it0 / 25, p0 = it0 % 25;
    const int tl1 = it1 / 25, p1 = it1 % 25;
    const bool val0 = dthr && (8 * g + tl0 < OH);
    const bool val1 = dthr && (8 * g + tl1 < OH);
    const int pos0 = (p0 / 5) * SEGW + 2 * tl0 + (p0 % 5);
    const int pos1 = (p1 / 5) * SEGW + 2 * tl1 + (p1 % 5);
    float acc0 = 0.0f, acc1 = 0.0f;

    #pragma unroll 1
    for (int ch = 0; ch < 8; ++ch) {
        __syncthreads();
        if (sval) {
            #pragma unroll
            for (int c4 = 0; c4 < 4; ++c4) {
                const float4 ev = {v[4*c4] * inv, v[4*c4+1] * inv,
                                   v[4*c4+2] * inv, v[4*c4+3] * inv};
                *(float4*)&band[bnd(t, c4)] = ev;
            }
        }
        __syncthreads();
        if (ch < 7 && sval) {
            const float* p = gp + (size_t)((ch + 1) * 16) * HW;
            #pragma unroll
            for (int k = 0; k < 16; ++k) v[k] = p[(size_t)k * HW];
        }
        if (t < 32) {
            const int tl = t >> 2, c4 = t & 3;
            float4 s = {0.0f, 0.0f, 0.0f, 0.0f};
            #pragma unroll
            for (int r = 0; r < 5; ++r)
                #pragma unroll
                for (int k = 0; k < 5; ++k) {
                    const float4 ev = *(const float4*)&band[bnd(r * SEGW + 2 * tl + k, c4)];
                    s.x += ev.x; s.y += ev.y; s.z += ev.z; s.w += ev.w;
                }
            *(float4*)&Sl[tl * 16 + c4 * 4] = s;
        }
        __syncthreads();
        if (dthr) {
            float4 sv[4];
            #pragma unroll
            for (int c4 = 0; c4 < 4; ++c4) sv[c4] = *(const float4*)&Sl[tl0 * 16 + c4 * 4];
            #pragma unroll
            for (int c4 = 0; c4 < 4; ++c4) {
                const float4 ev = *(const float4*)&band[bnd(pos0, c4)];
                acc0 += ev.x * sv[c4].x + ev.y * sv[c4].y + ev.z * sv[c4].z + ev.w * sv[c4].w;
            }
            if (tl1 != tl0) {
                #pragma unroll
                for (int c4 = 0; c4 < 4; ++c4) sv[c4] = *(const float4*)&Sl[tl1 * 16 + c4 * 4];
            }
            #pragma unroll
            for (int c4 = 0; c4 < 4; ++c4) {
                const float4 ev = *(const float4*)&band[bnd(pos1, c4)];
                acc1 += ev.x * sv[c4].x + ev.y * sv[c4].y + ev.z * sv[c4].z + ev.w * sv[c4].w;
            }
        }
    }

    float m = 0.0f;
    if (val0) m = fmaxf(m, 1.0f - acc0 * 0.04f);
    if (val1) m = fmaxf(m, 1.0f - acc1 * 0.04f);
    #pragma unroll
    for (int off = 1; off < 64; off <<= 1) m = fmaxf(m, __shfl_xor(m, off));
    if ((t & 63) == 0) wmax[t >> 6] = m;
    __syncthreads();
    if (t == 0) slots[lb] = fmaxf(wmax[0], wmax[1]);
}

// ---------------- finalize: 3840 slots -> loss ----------------
__global__ __launch_bounds__(128) void finalize(const float* __restrict__ slots,
                                                const int* __restrict__ label,
                                                float* __restrict__ out) {
    const int t = threadIdx.x;
    __shared__ float bmax[32];
    const int b = t >> 2, j = t & 3;          // 4 threads per b
    float m = 0.0f;
    for (int i = j; i < 120; i += 4) m = fmaxf(m, slots[b * 120 + i]);
    m = fmaxf(m, __shfl_xor(m, 1));
    m = fmaxf(m, __shfl_xor(m, 2));
    if (j == 0) bmax[b] = m;
    __syncthreads();
    if (t == 0) {
        float fs = 0.0f, rs = 0.0f, fc = 0.0f, rc = 0.0f;
        for (int b2 = 0; b2 < NB; ++b2) {
            const float tb  = bmax[b2];
            const float lbv = (float)label[b2];
            fs += tb * lbv;          fc += lbv;
            rs += tb * (1.0f - lbv); rc += (1.0f - lbv);
        }
        const float loss = 1.0f - fs / fc + rs / rc;
        out[0] = fmaxf(loss, 0.0f);
    }
}

extern "C" void kernel_launch(void* const* d_in, const int* in_sizes, int n_in,
                              void* d_out, int out_size, void* d_ws, size_t ws_size,
                              hipStream_t stream) {
    const float* feature = (const float*)d_in[0];
    const int* label     = (const int*)d_in[1];
    float* out   = (float*)d_out;
    float* slots = (float*)d_ws;
    float* map   = (float*)((char*)d_ws + MAP_OFF);
    unsigned* e  = (unsigned*)((char*)d_ws + E_OFF);

    const bool big = ws_size >= WS_BIG_NEED;   // fixed per session -> deterministic
    if (big) {
        norm_kernel<1><<<NB * 125, 256, 0, stream>>>(feature, map, e);
        seg_bf16_kernel<<<NBLK, 128, 0, stream>>>(e, slots);
    } else {
        norm_kernel<0><<<NB * 125, 256, 0, stream>>>(feature, map, nullptr);
        seg_f32_kernel<<<NBLK, 128, 0, stream>>>(feature, map, slots);
    }
    finalize<<<1, 128, 0, stream>>>(slots, label, out);
}

// Round 11
// 57.756 us; speedup vs baseline: 1.1932x; 1.1877x over previous
//
#include <hip/hip_runtime.h>

// Problem constants (fixed by reference setup_inputs)
#define NB 32
#define NC 128
#define NH 63
#define NW 63
#define HW 3969          // 63*63
#define NPIX 3969
#define OH 30            // (63-5)/2+1
#define OW 30
#define SEGW 19          // band cols per segment (tiles 8g..8g+7 -> cols 16g..16g+18)
#define POSN (5*SEGW)    // 95
#define NSEG 4
#define NSTRIP (NB*OH)   // 960
#define NBLK (NSTRIP*NSEG) // 3840

// ws layout (bytes):
//   [0, 15360)        : 3840 per-block result slots (float)  -- all written each launch
//   [15360, 523392)   : inv-norm map, 32*3969 floats (fallback path only)
//   [523392, +32.5MB) : fp16 e-copy, 32*3969*64 uints (big path only)
#define MAP_OFF  ((size_t)NBLK * 4)
#define E_OFF    (MAP_OFF + (size_t)NB * NPIX * 4)
#define E_BYTES  ((size_t)NB * NPIX * 64 * 4)
#define WS_BIG_NEED (E_OFF + E_BYTES)

typedef _Float16 half2_t __attribute__((ext_vector_type(2)));
__device__ __forceinline__ half2_t u2h(unsigned u) { return __builtin_bit_cast(half2_t, u); }
__device__ __forceinline__ unsigned h2u(half2_t h) { return __builtin_bit_cast(unsigned, h); }

// 2-way fp16 dot with fp32 accumulate (v_dot2_f32_f16); exact-unpack fallback.
__device__ __forceinline__ float dot2(unsigned a, unsigned b, float c) {
#if __has_builtin(__builtin_amdgcn_fdot2)
    return __builtin_amdgcn_fdot2(u2h(a), u2h(b), c, false);
#else
    const half2_t x = u2h(a), y = u2h(b);
    c = fmaf((float)x[0], (float)y[0], c);
    return fmaf((float)x[1], (float)y[1], c);
#endif
}

// ---------------- k1: per-pixel inv-norm (+ fp16 e-copy on big path) ----------------
// 8 threads per pixel (16 channels each); block = 32 pixels. Atomic-free reduce.
template<int BIG>
__global__ __launch_bounds__(256) void norm_kernel(const float* __restrict__ f,
                                                   float* __restrict__ map,
                                                   unsigned* __restrict__ e) {
    const int b      = blockIdx.x / 125;
    const int grp    = blockIdx.x % 125;
    const int t      = threadIdx.x;
    const int chunk  = t >> 5;           // 0..7 -> channels 16*chunk..+15
    const int pixloc = t & 31;
    const int pix    = grp * 32 + pixloc;
    const bool valid = pix < NPIX;

    __shared__ float sq[8][32];
    __shared__ float sinv[32];

    float v[16]; float ss = 0.0f;
    if (valid) {
        const float* p = f + (size_t)b * NC * HW + (size_t)chunk * 16 * HW + pix;
        #pragma unroll
        for (int k = 0; k < 16; ++k) v[k] = p[(size_t)k * HW];
        #pragma unroll
        for (int k = 0; k < 16; ++k) ss = fmaf(v[k], v[k], ss);
    }
    sq[chunk][pixloc] = ss;
    __syncthreads();
    if (t < 32) {
        float s = 0.0f;
        #pragma unroll
        for (int k = 0; k < 8; ++k) s += sq[k][t];
        const float inv = rsqrtf(fmaxf(s, 1e-24f));
        sinv[t] = inv;
        if (!BIG && grp * 32 + t < NPIX) map[b * NPIX + grp * 32 + t] = inv;
    }
    __syncthreads();
    if (BIG && valid) {
        const float inv = sinv[pixloc];
        unsigned u[8];
        #pragma unroll
        for (int j = 0; j < 8; ++j) {
            const half2_t h2 = {(_Float16)(v[2*j] * inv), (_Float16)(v[2*j+1] * inv)};
            u[j] = h2u(h2);
        }
        unsigned* dst = e + ((size_t)b * NPIX + pix) * 64 + chunk * 8;
        *(uint4*)dst       = make_uint4(u[0], u[1], u[2], u[3]);
        *(uint4*)(dst + 4) = make_uint4(u[4], u[5], u[6], u[7]);
    }
}

// ---------------- k2 (big): single-stage fp16 segment kernel ----------------
// s[tile][p] = 1 - (1/25) e_p . S_tile. Band swizzle: granule (slot+pos)&15,
// identical on write and read (both-sides rule).
__global__ __launch_bounds__(128) void seg_fp16_kernel(const unsigned* __restrict__ e,
                                                       float* __restrict__ slots) {
    const int lb    = (blockIdx.x & 7) * (NBLK / 8) + (blockIdx.x >> 3);
    const int strip = lb >> 2, g = lb & 3;
    const int b = strip / OH, oi = strip % OH;
    const int y0 = oi * 2, xlo = 16 * g;
    const int t = threadIdx.x;

    __shared__ unsigned band[POSN * 64];   // 24320 B: [pos][64 uints = 128 fp16]
    __shared__ uint4 Slh[16][8];           // 2 KB: per-(slot, tile) S as 8 half2
    __shared__ float wmax[2];

    const unsigned* eb = e + (size_t)b * NPIX * 64;

    // ---- stage whole band (12 coalesced rounds) ----
    #pragma unroll 1
    for (int i = t; i < POSN * 16; i += 128) {
        const int pos = i >> 4, slot = i & 15;
        const int r = pos / SEGW, xx = pos - r * SEGW;
        const int x = xlo + xx;
        uint4 v = make_uint4(0u, 0u, 0u, 0u);
        if (x < NW) v = *(const uint4*)(eb + (size_t)((y0 + r) * NW + x) * 64 + slot * 4);
        *(uint4*)&band[pos * 64 + (((slot + pos) & 15) << 2)] = v;
    }
    __syncthreads();

    // ---- S sums in packed half2: thread (tl = t>>4, slot = t&15) ----
    {
        const int tl = t >> 4, slot = t & 15;
        half2_t s0 = u2h(0u), s1 = u2h(0u), s2 = u2h(0u), s3 = u2h(0u);
        #pragma unroll
        for (int r = 0; r < 5; ++r)
            #pragma unroll
            for (int k = 0; k < 5; ++k) {
                const int pos = r * SEGW + 2 * tl + k;
                const uint4 v = *(const uint4*)&band[pos * 64 + (((slot + pos) & 15) << 2)];
                s0 += u2h(v.x); s1 += u2h(v.y); s2 += u2h(v.z); s3 += u2h(v.w);
            }
        Slh[slot][tl] = make_uint4(h2u(s0), h2u(s1), h2u(s2), h2u(s3));
    }
    __syncthreads();

    // ---- dots via v_dot2_f32_f16: thread t<100 owns items 2t, 2t+1 of 8*25 ----
    float m = 0.0f;
    if (t < 100) {
        const int it0 = 2 * t, it1 = 2 * t + 1;
        const int tl0 = it0 / 25, p0 = it0 % 25;
        const int tl1 = it1 / 25, p1 = it1 % 25;
        const bool val0 = (8 * g + tl0 < OH);
        const bool val1 = (8 * g + tl1 < OH);
        const int pos0 = (p0 / 5) * SEGW + 2 * tl0 + (p0 % 5);
        const int pos1 = (p1 / 5) * SEGW + 2 * tl1 + (p1 % 5);
        float acc0 = 0.0f, acc1 = 0.0f;
        #pragma unroll
        for (int slot = 0; slot < 16; ++slot) {
            const uint4 sv = Slh[slot][tl0];
            const uint4 v  = *(const uint4*)&band[pos0 * 64 + (((slot + pos0) & 15) << 2)];
            acc0 = dot2(v.x, sv.x, acc0);
            acc0 = dot2(v.y, sv.y, acc0);
            acc0 = dot2(v.z, sv.z, acc0);
            acc0 = dot2(v.w, sv.w, acc0);
        }
        #pragma unroll
        for (int slot = 0; slot < 16; ++slot) {
            const uint4 sv = Slh[slot][tl1];
            const uint4 v  = *(const uint4*)&band[pos1 * 64 + (((slot + pos1) & 15) << 2)];
            acc1 = dot2(v.x, sv.x, acc1);
            acc1 = dot2(v.y, sv.y, acc1);
            acc1 = dot2(v.z, sv.z, acc1);
            acc1 = dot2(v.w, sv.w, acc1);
        }
        if (val0) m = fmaxf(m, 1.0f - acc0 * 0.04f);
        if (val1) m = fmaxf(m, 1.0f - acc1 * 0.04f);
    }
    #pragma unroll
    for (int off = 1; off < 64; off <<= 1) m = fmaxf(m, __shfl_xor(m, off));
    if ((t & 63) == 0) wmax[t >> 6] = m;
    __syncthreads();
    if (t == 0) slots[lb] = fmaxf(wmax[0], wmax[1]);   // >= 0 by construction
}

// ---------------- k2 (fallback): chunked fp32 kernel, pass-1 via map ----------------
__device__ __forceinline__ int bnd(int pos, int c4) {
    return pos * 16 + (((c4 + (pos >> 1)) & 3) << 2);
}

__global__ __launch_bounds__(128) void seg_f32_kernel(const float* __restrict__ f,
                                                      const float* __restrict__ map,
                                                      float* __restrict__ slots) {
    const int lb    = (blockIdx.x & 7) * (NBLK / 8) + (blockIdx.x >> 3);
    const int strip = lb >> 2, g = lb & 3;
    const int b = strip / OH, oi = strip % OH;
    const int y0 = oi * 2, xlo = 16 * g;
    const int t = threadIdx.x;

    __shared__ __align__(16) float band[POSN * 16];
    __shared__ __align__(16) float Sl[8 * 16];
    __shared__ float wmax[2];

    const int  sr   = (t < POSN) ? t / SEGW : 0;
    const int  sxx  = (t < POSN) ? t % SEGW : 0;
    const bool sval = (t < POSN) && (xlo + sxx < NW);
    const float* gp = f + (size_t)b * NC * HW + (size_t)(y0 + sr) * NW + xlo + sxx;
    const float inv = sval ? map[b * NPIX + (y0 + sr) * NW + xlo + sxx] : 0.0f;

    float v[16];
    if (sval) {
        #pragma unroll
        for (int k = 0; k < 16; ++k) v[k] = gp[(size_t)k * HW];
    }

    const bool dthr = t < 100;
    const int it0 = 2 * t, it1 = 2 * t + 1;
    const int tl0 = it0 / 25, p0 = it0 % 25;
    const int tl1 = it1 / 25, p1 = it1 % 25;
    const bool val0 = dthr && (8 * g + tl0 < OH);
    const bool val1 = dthr && (8 * g + tl1 < OH);
    const int pos0 = (p0 / 5) * SEGW + 2 * tl0 + (p0 % 5);
    const int pos1 = (p1 / 5) * SEGW + 2 * tl1 + (p1 % 5);
    float acc0 = 0.0f, acc1 = 0.0f;

    #pragma unroll 1
    for (int ch = 0; ch < 8; ++ch) {
        __syncthreads();
        if (sval) {
            #pragma unroll
            for (int c4 = 0; c4 < 4; ++c4) {
                const float4 ev = {v[4*c4] * inv, v[4*c4+1] * inv,
                                   v[4*c4+2] * inv, v[4*c4+3] * inv};
                *(float4*)&band[bnd(t, c4)] = ev;
            }
        }
        __syncthreads();
        if (ch < 7 && sval) {
            const float* p = gp + (size_t)((ch + 1) * 16) * HW;
            #pragma unroll
            for (int k = 0; k < 16; ++k) v[k] = p[(size_t)k * HW];
        }
        if (t < 32) {
            const int tl = t >> 2, c4 = t & 3;
            float4 s = {0.0f, 0.0f, 0.0f, 0.0f};
            #pragma unroll
            for (int r = 0; r < 5; ++r)
                #pragma unroll
                for (int k = 0; k < 5; ++k) {
                    const float4 ev = *(const float4*)&band[bnd(r * SEGW + 2 * tl + k, c4)];
                    s.x += ev.x; s.y += ev.y; s.z += ev.z; s.w += ev.w;
                }
            *(float4*)&Sl[tl * 16 + c4 * 4] = s;
        }
        __syncthreads();
        if (dthr) {
            float4 sv[4];
            #pragma unroll
            for (int c4 = 0; c4 < 4; ++c4) sv[c4] = *(const float4*)&Sl[tl0 * 16 + c4 * 4];
            #pragma unroll
            for (int c4 = 0; c4 < 4; ++c4) {
                const float4 ev = *(const float4*)&band[bnd(pos0, c4)];
                acc0 += ev.x * sv[c4].x + ev.y * sv[c4].y + ev.z * sv[c4].z + ev.w * sv[c4].w;
            }
            if (tl1 != tl0) {
                #pragma unroll
                for (int c4 = 0; c4 < 4; ++c4) sv[c4] = *(const float4*)&Sl[tl1 * 16 + c4 * 4];
            }
            #pragma unroll
            for (int c4 = 0; c4 < 4; ++c4) {
                const float4 ev = *(const float4*)&band[bnd(pos1, c4)];
                acc1 += ev.x * sv[c4].x + ev.y * sv[c4].y + ev.z * sv[c4].z + ev.w * sv[c4].w;
            }
        }
    }

    float m = 0.0f;
    if (val0) m = fmaxf(m, 1.0f - acc0 * 0.04f);
    if (val1) m = fmaxf(m, 1.0f - acc1 * 0.04f);
    #pragma unroll
    for (int off = 1; off < 64; off <<= 1) m = fmaxf(m, __shfl_xor(m, off));
    if ((t & 63) == 0) wmax[t >> 6] = m;
    __syncthreads();
    if (t == 0) slots[lb] = fmaxf(wmax[0], wmax[1]);
}

// ---------------- finalize: 3840 slots -> loss ----------------
__global__ __launch_bounds__(128) void finalize(const float* __restrict__ slots,
                                                const int* __restrict__ label,
                                                float* __restrict__ out) {
    const int t = threadIdx.x;
    __shared__ float bmax[32];
    const int b = t >> 2, j = t & 3;          // 4 threads per b
    float m = 0.0f;
    for (int i = j; i < 120; i += 4) m = fmaxf(m, slots[b * 120 + i]);
    m = fmaxf(m, __shfl_xor(m, 1));
    m = fmaxf(m, __shfl_xor(m, 2));
    if (j == 0) bmax[b] = m;
    __syncthreads();
    if (t == 0) {
        float fs = 0.0f, rs = 0.0f, fc = 0.0f, rc = 0.0f;
        for (int b2 = 0; b2 < NB; ++b2) {
            const float tb  = bmax[b2];
            const float lbv = (float)label[b2];
            fs += tb * lbv;          fc += lbv;
            rs += tb * (1.0f - lbv); rc += (1.0f - lbv);
        }
        const float loss = 1.0f - fs / fc + rs / rc;
        out[0] = fmaxf(loss, 0.0f);
    }
}

extern "C" void kernel_launch(void* const* d_in, const int* in_sizes, int n_in,
                              void* d_out, int out_size, void* d_ws, size_t ws_size,
                              hipStream_t stream) {
    const float* feature = (const float*)d_in[0];
    const int* label     = (const int*)d_in[1];
    float* out   = (float*)d_out;
    float* slots = (float*)d_ws;
    float* map   = (float*)((char*)d_ws + MAP_OFF);
    unsigned* e  = (unsigned*)((char*)d_ws + E_OFF);

    const bool big = ws_size >= WS_BIG_NEED;   // fixed per session -> deterministic
    if (big) {
        norm_kernel<1><<<NB * 125, 256, 0, stream>>>(feature, map, e);
        seg_fp16_kernel<<<NBLK, 128, 0, stream>>>(e, slots);
    } else {
        norm_kernel<0><<<NB * 125, 256, 0, stream>>>(feature, map, nullptr);
        seg_f32_kernel<<<NBLK, 128, 0, stream>>>(feature, map, slots);
    }
    finalize<<<1, 128, 0, stream>>>(slots, label, out);
}

// Round 13
// 38.467 us; speedup vs baseline: 1.7915x; 1.5014x over previous
//
#include <hip/hip_runtime.h>

// Problem constants (fixed by reference setup_inputs)
#define NB 32
#define NC 128
#define NH 63
#define NW 63
#define HW 3969          // 63*63
#define OH 30            // (63-5)/2+1
#define SEGW 19          // band cols per segment (tiles 8g..8g+7 -> cols 16g..16g+18)
#define POSN 95          // 5*SEGW
#define NBLK 3840        // 32*30*4

typedef _Float16 half2_t __attribute__((ext_vector_type(2)));
__device__ __forceinline__ half2_t u2h(unsigned u) { return __builtin_bit_cast(half2_t, u); }
__device__ __forceinline__ unsigned h2u(half2_t h) { return __builtin_bit_cast(unsigned, h); }

// 2-way fp16 dot with fp32 accumulate (v_dot2_f32_f16); exact-unpack fallback.
__device__ __forceinline__ float dot2(unsigned a, unsigned b, float c) {
#if __has_builtin(__builtin_amdgcn_fdot2)
    return __builtin_amdgcn_fdot2(u2h(a), u2h(b), c, false);
#else
    const half2_t x = u2h(a), y = u2h(b);
    c = fmaf((float)x[0], (float)y[0], c);
    return fmaf((float)x[1], (float)y[1], c);
#endif
}

__device__ __forceinline__ unsigned pk16(float a, float b) {
#if __has_builtin(__builtin_amdgcn_cvt_pkrtz)
    // builtin returns __fp16x2; bit_cast its own type to u32 (no conversion)
    return __builtin_bit_cast(unsigned, __builtin_amdgcn_cvt_pkrtz(a, b));
#else
    const half2_t h = {(_Float16)a, (_Float16)b};
    return h2u(h);
#endif
}

// One block per (b, oi, segment). Stages raw f as packed fp16 (band), exact fp32
// norms in stager registers, then S = sum_q f_q*inv_q (packed-half2 fma) and
// s[p] = 1 - (1/25) * (f_p . S) * inv_p  (v_dot2_f32_f16).
// Band granule swizzle: logical uint4-granule gl of row pos lives at (gl+pos)&15
// -- applied identically on write and read (both-sides rule).
// NOTE: bare launch_bounds -- a min-waves clause collapses the VGPR budget below
// the live set and spills (R6: 2.6 GB scratch, R7: 58 MB scratch).
__global__ __launch_bounds__(256) void seg_fused(const float* __restrict__ f,
                                                 float* __restrict__ slots) {
    // XCD-chunked swizzle (bijective: 3840 = 8*480): consecutive logical blocks =
    // the 4 segments of one strip, then adjacent strips -> same-XCD L2 reuse.
    const int lb    = (blockIdx.x & 7) * (NBLK / 8) + (blockIdx.x >> 3);
    const int strip = lb >> 2, g = lb & 3;
    const int b = strip / OH, oi = strip % OH;
    const int y0 = oi * 2, xlo = 16 * g;
    const int t = threadIdx.x;

    __shared__ unsigned band[POSN * 64];   // 24320 B: [pos][64 uints = 128 fp16]
    __shared__ float sq2[POSN][2];         // per-pos sumsq halves
    __shared__ float sinv[POSN];           // fp32 inv-norm per pos
    __shared__ unsigned sinvh[POSN];       // inv as splatted half2
    __shared__ uint4 Slh[16][8];           // per-(slot, tile) S as 8 half2
    __shared__ float wmax[4];

    // ---- stage: t<190 -> (pos = t mod 95, half = t/95); 4 chunks of 16 ch ----
    if (t < 2 * POSN) {
        const int pos  = (t >= POSN) ? t - POSN : t;
        const int half = (t >= POSN) ? 1 : 0;
        const int r = pos / SEGW, xx = pos % SEGW;
        const int x = xlo + xx;
        float ss = 0.0f;
        if (x < NW) {
            const float* gp = f + (size_t)b * NC * HW + (size_t)(half * 64) * HW
                                + (size_t)(y0 + r) * NW + x;
            #pragma unroll
            for (int ch = 0; ch < 4; ++ch) {
                float v[16];
                #pragma unroll
                for (int k = 0; k < 16; ++k) v[k] = gp[(size_t)(ch * 16 + k) * HW];
                #pragma unroll
                for (int k = 0; k < 16; ++k) ss = fmaf(v[k], v[k], ss);
                unsigned u[8];
                #pragma unroll
                for (int j = 0; j < 8; ++j) u[j] = pk16(v[2 * j], v[2 * j + 1]);
                const int c = half * 4 + ch;          // global chunk 0..7
                *(uint4*)&band[pos * 64 + (((2 * c     + pos) & 15) << 2)] =
                    make_uint4(u[0], u[1], u[2], u[3]);
                *(uint4*)&band[pos * 64 + (((2 * c + 1 + pos) & 15) << 2)] =
                    make_uint4(u[4], u[5], u[6], u[7]);
            }
        } else {
            #pragma unroll
            for (int j = 0; j < 8; ++j)               // zero own half of the row
                ((uint4*)band)[pos * 16 + half * 8 + j] = make_uint4(0u, 0u, 0u, 0u);
        }
        sq2[pos][half] = ss;
    }
    __syncthreads();
    if (t < POSN) {
        const float s   = sq2[t][0] + sq2[t][1];
        const float inv = (s > 0.0f) ? rsqrtf(s) : 0.0f;
        sinv[t] = inv;
        const half2_t i2 = {(_Float16)inv, (_Float16)inv};
        sinvh[t] = h2u(i2);
    }
    __syncthreads();

    // ---- S-phase: t<128 -> (tl = t>>4, slot = t&15), s += f_q * inv_q ----
    if (t < 128) {
        const int tl = t >> 4, slot = t & 15;
        half2_t s0 = u2h(0u), s1 = u2h(0u), s2 = u2h(0u), s3 = u2h(0u);
        #pragma unroll
        for (int r = 0; r < 5; ++r)
            #pragma unroll
            for (int k = 0; k < 5; ++k) {
                const int pos = r * SEGW + 2 * tl + k;
                const uint4 v = *(const uint4*)&band[pos * 64 + (((slot + pos) & 15) << 2)];
                const half2_t iv = u2h(sinvh[pos]);
                s0 = u2h(v.x) * iv + s0;
                s1 = u2h(v.y) * iv + s1;
                s2 = u2h(v.z) * iv + s2;
                s3 = u2h(v.w) * iv + s3;
            }
        Slh[slot][tl] = make_uint4(h2u(s0), h2u(s1), h2u(s2), h2u(s3));
    }
    __syncthreads();

    // ---- dots: t<200, one (tile, p) item each ----
    float m = 0.0f;
    if (t < 200) {
        const int tl = t / 25, p = t % 25;
        if (8 * g + tl < OH) {
            const int pos = (p / 5) * SEGW + 2 * tl + (p % 5);
            float acc = 0.0f;
            #pragma unroll
            for (int slot = 0; slot < 16; ++slot) {
                const uint4 sv = Slh[slot][tl];
                const uint4 v  = *(const uint4*)&band[pos * 64 + (((slot + pos) & 15) << 2)];
                acc = dot2(v.x, sv.x, acc);
                acc = dot2(v.y, sv.y, acc);
                acc = dot2(v.z, sv.z, acc);
                acc = dot2(v.w, sv.w, acc);
            }
            m = fmaxf(0.0f, 1.0f - acc * sinv[pos] * 0.04f);
        }
    }
    #pragma unroll
    for (int off = 1; off < 64; off <<= 1) m = fmaxf(m, __shfl_xor(m, off));
    if ((t & 63) == 0) wmax[t >> 6] = m;
    __syncthreads();
    if (t == 0)
        slots[lb] = fmaxf(fmaxf(wmax[0], wmax[1]), fmaxf(wmax[2], wmax[3]));
}

// ---------------- finalize: 3840 slots -> loss ----------------
__global__ __launch_bounds__(128) void finalize(const float* __restrict__ slots,
                                                const int* __restrict__ label,
                                                float* __restrict__ out) {
    const int t = threadIdx.x;
    __shared__ float bmax[32];
    const int b = t >> 2, j = t & 3;          // 4 threads per b
    float m = 0.0f;
    for (int i = j; i < 120; i += 4) m = fmaxf(m, slots[b * 120 + i]);
    m = fmaxf(m, __shfl_xor(m, 1));
    m = fmaxf(m, __shfl_xor(m, 2));
    if (j == 0) bmax[b] = m;
    __syncthreads();
    if (t == 0) {
        float fs = 0.0f, rs = 0.0f, fc = 0.0f, rc = 0.0f;
        for (int b2 = 0; b2 < NB; ++b2) {
            const float tb  = bmax[b2];
            const float lbv = (float)label[b2];
            fs += tb * lbv;          fc += lbv;
            rs += tb * (1.0f - lbv); rc += (1.0f - lbv);
        }
        const float loss = 1.0f - fs / fc + rs / rc;
        out[0] = fmaxf(loss, 0.0f);
    }
}

extern "C" void kernel_launch(void* const* d_in, const int* in_sizes, int n_in,
                              void* d_out, int out_size, void* d_ws, size_t ws_size,
                              hipStream_t stream) {
    const float* feature = (const float*)d_in[0];
    const int* label     = (const int*)d_in[1];
    float* out   = (float*)d_out;
    float* slots = (float*)d_ws;   // 3840 floats, fully rewritten each launch

    seg_fused<<<NBLK, 256, 0, stream>>>(feature, slots);
    finalize<<<1, 128, 0, stream>>>(slots, label, out);
}